// Round 5
// baseline (400.456 us; speedup 1.0000x reference)
//
#include <hip/hip_runtime.h>

// LinearQuant: out[32,8192] = x[32,8192] @ (int8-valued-int32 W[8192,8192] * scaler)
// HBM floor: 256 MiB weight stream (+128 MiB partial round-trip) ~57 us @ 6.7 TB/s.
//
// R4 vs R3 (main kernel ~130 us, LDS-pipe bound):
//   R3 read 128 B of x from LDS per 4 B weight (32 fmas/weight, 8x ds_read_b128/k
//   for ONE column). LDS pipe (~85 B/cyc/CU) only has ~10x HBM BW; we needed 32x.
//   Fix: 4 columns per thread -> same 8 ds_read_b128 per k feed 128 fmas,
//   LDS/weight drops 4x. KSPLIT 32->64 for 8 waves/CU (2 blocks/CU).
// (R5 = R4 resubmitted: the R4 bench died in GPU acquisition, never ran.)

#define IN_F   8192
#define OUT_F  8192
#define BATCH  32
#define KSPLIT 64
#define KCHUNK (IN_F / KSPLIT)   // 128 rows of W per block
#define CPT    4                 // columns per thread

// xt[k][b] = x[b][k] * scaler   (k-major: a block's chunk is contiguous)
__global__ void prep_x_kernel(const float* __restrict__ x,
                              const float* __restrict__ scaler,
                              float* __restrict__ xt) {
    int i = blockIdx.x * 256 + threadIdx.x;   // 0 .. BATCH*IN_F-1
    int k = i >> 5;
    int b = i & 31;
    xt[i] = x[b * IN_F + k] * scaler[0];      // 1 MiB; strided reads absorbed by L2
}

__global__ __launch_bounds__(256, 2)
void lq_main_kernel(const int* __restrict__ w,
                    const float* __restrict__ xt,
                    float* __restrict__ part) {
    __shared__ float4 xs[KCHUNK * (BATCH / 4)];       // 16 KB: k-chunk of x
    const int tid = threadIdx.x;
    const int colbase = blockIdx.x * (256 * CPT) + tid;  // + c*256, c in [0,4)
    const int kc  = blockIdx.y;
    const int k0  = kc * KCHUNK;

    // Stage x chunk: 1024 float4, 256 threads -> 4 each, coalesced.
    const float4* xg = (const float4*)(xt + (size_t)k0 * BATCH);
#pragma unroll
    for (int j = 0; j < (KCHUNK * BATCH / 4) / 256; ++j)
        xs[j * 256 + tid] = xg[j * 256 + tid];
    __syncthreads();

    float acc[CPT][BATCH];
#pragma unroll
    for (int c = 0; c < CPT; ++c)
#pragma unroll
        for (int b = 0; b < BATCH; ++b) acc[c][b] = 0.0f;

    const int* wp = w + (size_t)k0 * OUT_F + colbase;

#pragma unroll 4
    for (int k = 0; k < KCHUNK; ++k) {
        // 4 coalesced weight loads (offsets 0,1KB,2KB,3KB fold into the instr)
        float wv[CPT];
#pragma unroll
        for (int c = 0; c < CPT; ++c)
            wv[c] = (float)wp[(size_t)k * OUT_F + c * 256];
        const float4* xk = &xs[k * (BATCH / 4)];
#pragma unroll
        for (int q = 0; q < BATCH / 4; ++q) {         // 8x ds_read_b128 broadcast
            float4 xv = xk[q];
#pragma unroll
            for (int c = 0; c < CPT; ++c) {
                acc[c][4 * q + 0] = fmaf(xv.x, wv[c], acc[c][4 * q + 0]);
                acc[c][4 * q + 1] = fmaf(xv.y, wv[c], acc[c][4 * q + 1]);
                acc[c][4 * q + 2] = fmaf(xv.z, wv[c], acc[c][4 * q + 2]);
                acc[c][4 * q + 3] = fmaf(xv.w, wv[c], acc[c][4 * q + 3]);
            }
        }
    }

    // part[kc][b][col]
    float* pp = part + (size_t)kc * (BATCH * OUT_F) + colbase;
#pragma unroll
    for (int b = 0; b < BATCH; ++b)
#pragma unroll
        for (int c = 0; c < CPT; ++c)
            pp[(size_t)b * OUT_F + c * 256] = acc[c][b];
}

// out[i] = sum_c part[c][i]  (deterministic, coalesced)
__global__ void reduce_kernel(const float* __restrict__ part,
                              float* __restrict__ out) {
    int i = blockIdx.x * 256 + threadIdx.x;           // over BATCH*OUT_F/4
    float4 s = {0.f, 0.f, 0.f, 0.f};
    const float4* p4 = (const float4*)part;
#pragma unroll
    for (int c = 0; c < KSPLIT; ++c) {
        float4 v = p4[(size_t)c * (BATCH * OUT_F / 4) + i];
        s.x += v.x; s.y += v.y; s.z += v.z; s.w += v.w;
    }
    ((float4*)out)[i] = s;
}

extern "C" void kernel_launch(void* const* d_in, const int* in_sizes, int n_in,
                              void* d_out, int out_size, void* d_ws, size_t ws_size,
                              hipStream_t stream) {
    const float* x = (const float*)d_in[0];
    const int*   w = (const int*)d_in[1];
    const float* s = (const float*)d_in[2];
    float* out  = (float*)d_out;
    float* xt   = (float*)d_ws;                               // 1 MiB
    float* part = (float*)d_ws + (size_t)BATCH * IN_F;        // 64 MiB

    prep_x_kernel<<<dim3((BATCH * IN_F) / 256), dim3(256), 0, stream>>>(x, s, xt);

    lq_main_kernel<<<dim3(OUT_F / (256 * CPT), KSPLIT), dim3(256), 0, stream>>>(w, xt, part);

    reduce_kernel<<<dim3((BATCH * OUT_F / 4) / 256), dim3(256), 0, stream>>>(part, out);
}

// Round 9
// 386.383 us; speedup vs baseline: 1.0364x; 1.0364x over previous
//
#include <hip/hip_runtime.h>

// LinearQuant: out[32,8192] = x[32,8192] @ (int8-valued-int32 W[8192,8192] * scaler)
// HBM floor: 256 MiB weight stream; ~6.7 TB/s achievable (measured via harness fills).
//
// Evidence so far: R1(atomics,16w/CU)=375.9  R3(LDS,16w/CU)=378.8  R5(8w/CU)=400.5.
// => mains are near the HBM/issue floor; 16 waves/CU is the controlling variable;
//    R5 regressed on occupancy + doubled partials + spilled 64-deep reduce unroll.
// R6 design: CPT=2, KSPLIT=64 -> 1024 blocks, 16KB LDS, 4 blk/CU = 16 waves/CU,
//     strip-mined reduce, nontemporal weight loads / partial stores.
// R9 = R6 with compile fix: __builtin_nontemporal_load needs a NATIVE vector
//     type; HIP's float4 is a class. Use ext_vector_type(4) float for the
//     reduce kernel's vector loads. No other changes.

#define IN_F   8192
#define OUT_F  8192
#define BATCH  32
#define KSPLIT 64
#define KCHUNK (IN_F / KSPLIT)   // 128 rows of W per block
#define CPT    2                 // columns per thread

typedef float f32x4 __attribute__((ext_vector_type(4)));  // native vec: ok for nontemporal

// xt[k][b] = x[b][k] * scaler   (k-major: a block's chunk is contiguous)
__global__ void prep_x_kernel(const float* __restrict__ x,
                              const float* __restrict__ scaler,
                              float* __restrict__ xt) {
    int i = blockIdx.x * 256 + threadIdx.x;   // 0 .. BATCH*IN_F-1
    int k = i >> 5;
    int b = i & 31;
    xt[i] = x[b * IN_F + k] * scaler[0];      // 1 MiB; strided reads absorbed by L2
}

__global__ __launch_bounds__(256, 4)
void lq_main_kernel(const int* __restrict__ w,
                    const float* __restrict__ xt,
                    float* __restrict__ part) {
    __shared__ float4 xs[KCHUNK * (BATCH / 4)];       // 16 KB: k-chunk of x
    const int tid = threadIdx.x;
    const int colbase = blockIdx.x * (256 * CPT) + tid;  // + c*256, c in [0,2)
    const int kc  = blockIdx.y;
    const int k0  = kc * KCHUNK;

    // Stage x chunk: 1024 float4, 256 threads -> 4 each, contiguous = conflict-free.
    const float4* xg = (const float4*)(xt + (size_t)k0 * BATCH);
#pragma unroll
    for (int j = 0; j < (KCHUNK * BATCH / 4) / 256; ++j)
        xs[j * 256 + tid] = xg[j * 256 + tid];
    __syncthreads();

    float acc[CPT][BATCH];
#pragma unroll
    for (int c = 0; c < CPT; ++c)
#pragma unroll
        for (int b = 0; b < BATCH; ++b) acc[c][b] = 0.0f;

    const int* wp = w + (size_t)k0 * OUT_F + colbase;

#pragma unroll 4
    for (int k = 0; k < KCHUNK; ++k) {
        // 2 coalesced streaming weight loads (offsets 0,1KB fold into the instr)
        float wv[CPT];
#pragma unroll
        for (int c = 0; c < CPT; ++c)
            wv[c] = (float)__builtin_nontemporal_load(&wp[(size_t)k * OUT_F + c * 256]);
        const float4* xk = &xs[k * (BATCH / 4)];
#pragma unroll
        for (int q = 0; q < BATCH / 4; ++q) {         // 8x ds_read_b128 broadcast
            float4 xv = xk[q];
#pragma unroll
            for (int c = 0; c < CPT; ++c) {
                acc[c][4 * q + 0] = fmaf(xv.x, wv[c], acc[c][4 * q + 0]);
                acc[c][4 * q + 1] = fmaf(xv.y, wv[c], acc[c][4 * q + 1]);
                acc[c][4 * q + 2] = fmaf(xv.z, wv[c], acc[c][4 * q + 2]);
                acc[c][4 * q + 3] = fmaf(xv.w, wv[c], acc[c][4 * q + 3]);
            }
        }
    }

    // part[kc][b][col] — streaming, keep out of L2's way
    float* pp = part + (size_t)kc * (BATCH * OUT_F) + colbase;
#pragma unroll
    for (int b = 0; b < BATCH; ++b)
#pragma unroll
        for (int c = 0; c < CPT; ++c)
            __builtin_nontemporal_store(acc[c][b], &pp[(size_t)b * OUT_F + c * 256]);
}

// out[i] = sum_c part[c][i]  (deterministic, coalesced, strip-mined: no spills)
__global__ void reduce_kernel(const float* __restrict__ part,
                              float* __restrict__ out) {
    int i = blockIdx.x * 256 + threadIdx.x;           // over BATCH*OUT_F/4 f32x4s
    f32x4 s = {0.f, 0.f, 0.f, 0.f};
    const f32x4* p4 = (const f32x4*)part;
#pragma unroll 8
    for (int c = 0; c < KSPLIT; ++c) {                // 8 loads in flight max
        f32x4 v = __builtin_nontemporal_load(&p4[(size_t)c * (BATCH * OUT_F / 4) + i]);
        s += v;
    }
    ((f32x4*)out)[i] = s;
}

extern "C" void kernel_launch(void* const* d_in, const int* in_sizes, int n_in,
                              void* d_out, int out_size, void* d_ws, size_t ws_size,
                              hipStream_t stream) {
    const float* x = (const float*)d_in[0];
    const int*   w = (const int*)d_in[1];
    const float* s = (const float*)d_in[2];
    float* out  = (float*)d_out;
    float* xt   = (float*)d_ws;                               // 1 MiB
    float* part = (float*)d_ws + (size_t)BATCH * IN_F;        // 64 MiB

    prep_x_kernel<<<dim3((BATCH * IN_F) / 256), dim3(256), 0, stream>>>(x, s, xt);

    lq_main_kernel<<<dim3(OUT_F / (256 * CPT), KSPLIT), dim3(256), 0, stream>>>(w, xt, part);

    reduce_kernel<<<dim3((BATCH * OUT_F / 4) / 256), dim3(256), 0, stream>>>(part, out);
}

// Round 13
// 383.085 us; speedup vs baseline: 1.0453x; 1.0086x over previous
//
#include <hip/hip_runtime.h>

// LinearQuant: out[32,8192] = x[32,8192] @ (int8-valued-int32 W[8192,8192] * scaler)
// HBM floor: 256 MiB weight stream ~40 us @ 6.6 TB/s (harness fills hit 6.5-6.7).
//
// Measured: R1(atomics,no-LDS)=375.9  R3(LDS,partials32M)=378.8  R5(8w/CU)=400.5
//           R9(LDS,partials64M,CPT=2)=386.4.
// => R1's atomic epilogue was cheapest (no reduce kernel, no partial round-trip);
//    R3-R1=+2.9us =~ reduce+roundtrip cost minus atomic cost.
// R10 = R3's main (CPT=1, KSPLIT=32, 16 waves/CU, LDS broadcast x) + R1's atomic
//    epilogue (rotated by kc to spread same-address collisions) + nontemporal W.
//    Expect: -reduce kernel, -64MiB partial traffic, +1MiB memset, +8.4M atomics.
// (R13 = R10 resubmitted 3x: R10/R11/R12 benches all died in GPU acquisition.)

#define IN_F   8192
#define OUT_F  8192
#define BATCH  32
#define KSPLIT 32
#define KCHUNK (IN_F / KSPLIT)   // 256 rows of W per block

// xt[k][b] = x[b][k] * scaler   (k-major: a block's chunk is contiguous)
__global__ void prep_x_kernel(const float* __restrict__ x,
                              const float* __restrict__ scaler,
                              float* __restrict__ xt) {
    int i = blockIdx.x * 256 + threadIdx.x;   // 0 .. BATCH*IN_F-1
    int k = i >> 5;
    int b = i & 31;
    xt[i] = x[b * IN_F + k] * scaler[0];      // 1 MiB; strided reads absorbed by L2
}

__global__ __launch_bounds__(256, 4)
void lq_main_kernel(const int* __restrict__ w,
                    const float* __restrict__ xt,
                    float* __restrict__ out) {
    __shared__ float4 xs[KCHUNK * (BATCH / 4)];       // 32 KB: whole k-chunk of x
    const int tid = threadIdx.x;
    const int col = blockIdx.x * 256 + tid;           // output column (lane-coalesced)
    const int kc  = blockIdx.y;
    const int k0  = kc * KCHUNK;

    // Stage x chunk: 2048 float4, 256 threads -> 8 each, contiguous = conflict-free.
    const float4* xg = (const float4*)(xt + (size_t)k0 * BATCH);
#pragma unroll
    for (int j = 0; j < (KCHUNK * BATCH / 4) / 256; ++j)
        xs[j * 256 + tid] = xg[j * 256 + tid];
    __syncthreads();

    float acc[BATCH];
#pragma unroll
    for (int b = 0; b < BATCH; ++b) acc[b] = 0.0f;

    const int* wp = w + (size_t)k0 * OUT_F + col;

#pragma unroll 8
    for (int k = 0; k < KCHUNK; ++k) {
        // 1 coalesced streaming weight dword/lane (256 B/wave)
        float wv = (float)__builtin_nontemporal_load(&wp[(size_t)k * OUT_F]);
        const float4* xk = &xs[k * (BATCH / 4)];
#pragma unroll
        for (int q = 0; q < BATCH / 4; ++q) {         // 8x ds_read_b128 broadcast
            float4 xv = xk[q];
            acc[4 * q + 0] = fmaf(xv.x, wv, acc[4 * q + 0]);
            acc[4 * q + 1] = fmaf(xv.y, wv, acc[4 * q + 1]);
            acc[4 * q + 2] = fmaf(xv.z, wv, acc[4 * q + 2]);
            acc[4 * q + 3] = fmaf(xv.w, wv, acc[4 * q + 3]);
        }
    }

    // Atomic epilogue straight to out[b][col]; rotate b-order by kc so the 32
    // K-chunk blocks of the same column don't hammer one address in lockstep.
    float* op = out + col;
#pragma unroll
    for (int bb = 0; bb < BATCH; ++bb) {
        int b = (bb + kc) & (BATCH - 1);
        atomicAdd(op + (size_t)b * OUT_F, acc[b]);    // device-scope, XCD-safe
    }
}

extern "C" void kernel_launch(void* const* d_in, const int* in_sizes, int n_in,
                              void* d_out, int out_size, void* d_ws, size_t ws_size,
                              hipStream_t stream) {
    const float* x = (const float*)d_in[0];
    const int*   w = (const int*)d_in[1];
    const float* s = (const float*)d_in[2];
    float* out = (float*)d_out;
    float* xt  = (float*)d_ws;                                // 1 MiB scratch

    // d_out is poisoned to 0xAA before every timed call -> zero it for atomics.
    hipMemsetAsync(d_out, 0, (size_t)out_size * sizeof(float), stream);

    prep_x_kernel<<<dim3((BATCH * IN_F) / 256), dim3(256), 0, stream>>>(x, s, xt);

    lq_main_kernel<<<dim3(OUT_F / 256, KSPLIT), dim3(256), 0, stream>>>(w, xt, out);
}